// Round 13
// baseline (7368.954 us; speedup 1.0000x reference)
//
#include <hip/hip_runtime.h>
#include <cstdint>
#include <cstddef>

typedef unsigned short u16;

#define L_TOK 16384
#define DMODEL 256
#define NHEAD 8
#define HDIM 32

__device__ __forceinline__ float bf2f(u16 u) {
    union { unsigned int i; float f; } v; v.i = ((unsigned int)u) << 16; return v.f;
}
__device__ __forceinline__ u16 f2bf(float f) {
    union { unsigned int i; float f; } v; v.f = f;
    unsigned int i = v.i;
    unsigned int r = (i + 0x7FFFu + ((i >> 16) & 1u)) >> 16;
    return (u16)r;
}

// ---------------- sentinel fill (FLOAT output) ----------------
__global__ __launch_bounds__(256) void fill_kernel(float* __restrict__ out, int n, float v) {
    int t = blockIdx.x * 256 + threadIdx.x;
    if (t < n) out[t] = v;
}

// x[l*256+d] = src[d*16384+l]  (src is (C, H*W) f32, natural layout)
__global__ __launch_bounds__(256) void xpose_kernel(const float* __restrict__ in,
                                                    u16* __restrict__ out) {
    int idx = blockIdx.x * 256 + threadIdx.x;
    if (idx >= L_TOK * DMODEL) return;
    int d = idx / L_TOK, l = idx - d * L_TOK;
    out[(size_t)l * DMODEL + d] = f2bf(in[idx]);
}

// q = x + pos^T
__global__ __launch_bounds__(256) void addq_kernel(const u16* __restrict__ x,
                                                   const float* __restrict__ p,
                                                   u16* __restrict__ q) {
    int idx = blockIdx.x * 256 + threadIdx.x;
    int l = idx >> 8, d = idx & 255;
    q[idx] = f2bf(bf2f(x[idx]) + p[(size_t)d * L_TOK + l]);
}

// C[m,n] = sum_k A[m,k]*W[k,n] + bias[n]   (A bf16, W/bias f32, C bf16)
__global__ __launch_bounds__(256) void gemm_naive(const u16* __restrict__ A,
                                                  const float* __restrict__ W,
                                                  const float* __restrict__ bias,
                                                  u16* __restrict__ C,
                                                  int M, int N, int K, int relu) {
    int idx = blockIdx.x * 256 + threadIdx.x;
    if (idx >= M * N) return;
    int m = idx / N, n = idx - m * N;
    float s = bias[n];
    const u16* a = A + (size_t)m * K;
    for (int k = 0; k < K; k++)
        s += bf2f(a[k]) * W[(size_t)k * N + n];
    if (relu) s = fmaxf(s, 0.f);
    C[idx] = f2bf(s);
}

__global__ __launch_bounds__(256) void softmax_kernel(u16* __restrict__ aw, int total) {
    int t = blockIdx.x * blockDim.x + threadIdx.x;
    if (t >= total) return;
    u16* pp = aw + (size_t)t * 25;
    float v[25];
    float mx = -1e30f;
    for (int k = 0; k < 25; k++) { v[k] = bf2f(pp[k]); mx = fmaxf(mx, v[k]); }
    float s = 0.f;
    for (int k = 0; k < 25; k++) { v[k] = __expf(v[k] - mx); s += v[k]; }
    float inv = 1.f / s;
    for (int k = 0; k < 25; k++) pp[k] = f2bf(v[k] * inv);
}

__global__ __launch_bounds__(256) void sample_kernel(const u16* __restrict__ val,
                                                     const u16* __restrict__ aw,
                                                     const u16* __restrict__ off,
                                                     u16* __restrict__ out) {
    int tid = blockIdx.x * blockDim.x + threadIdx.x;
    int hd = tid & 31;
    int pair = tid >> 5;          // l*NH + n
    int n = pair & 7;
    int l = pair >> 3;
    int iy = l >> 7, ix = l & 127;
    float cx = (ix + 0.5f) * (1.f / 128.f);
    float cy = (iy + 0.5f) * (1.f / 128.f);
    const u16* o = off + (size_t)pair * 4;
    float bx = cx + bf2f(o[0]) * (0.025f / 8.f);
    float by = cy + bf2f(o[1]) * (0.025f / 8.f);
    float bw = 0.025f + bf2f(o[2]) * (0.025f / 8.f);
    float bh = 0.025f + bf2f(o[3]) * (0.025f / 8.f);
    const u16* awp = aw + (size_t)pair * 25;
    float acc = 0.f;
    for (int k = 0; k < 25; k++) {
        float gx = (float)(k % 5 - 2) * 0.25f;
        float gy = (float)(k / 5 - 2) * 0.25f;
        float xx = (bx + bw * gx) * 128.f - 0.5f;
        float yy = (by + bh * gy) * 128.f - 0.5f;
        float x0 = floorf(xx), y0 = floorf(yy);
        float a_ = bf2f(awp[k]);
        for (int dy = 0; dy < 2; dy++) {
            for (int dx = 0; dx < 2; dx++) {
                float xi = x0 + dx, yi = y0 + dy;
                if (xi >= 0.f && xi < 128.f && yi >= 0.f && yi < 128.f) {
                    float w_ = (1.f - fabsf(xx - xi)) * (1.f - fabsf(yy - yi));
                    int idx = (int)yi * 128 + (int)xi;
                    acc += a_ * w_ * bf2f(val[(size_t)idx * 256 + n * 32 + hd]);
                }
            }
        }
    }
    out[(size_t)l * 256 + n * 32 + hd] = f2bf(acc);
}

// LN writing bf16 (intermediate layers)
__global__ __launch_bounds__(256) void ln_naive(const u16* __restrict__ xin,
                                                const u16* __restrict__ delta,
                                                const float* __restrict__ g,
                                                const float* __restrict__ b,
                                                u16* __restrict__ out) {
    int row = blockIdx.x * 256 + threadIdx.x;
    if (row >= L_TOK) return;
    size_t base = (size_t)row * 256;
    float sum = 0.f, sq = 0.f;
    for (int d = 0; d < 256; d++) {
        float v = bf2f(xin[base + d]) + bf2f(delta[base + d]);
        sum += v; sq += v * v;
    }
    float m = sum * (1.f / 256.f);
    float var = sq * (1.f / 256.f) - m * m;
    float r = rsqrtf(var + 1e-5f);
    for (int d = 0; d < 256; d++) {
        float v = bf2f(xin[base + d]) + bf2f(delta[base + d]);
        out[base + d] = f2bf((v - m) * r * g[d] + b[d]);
    }
}

// final LN writes FLOAT32 — d_out is the reference's output dtype (f32)
__global__ __launch_bounds__(256) void ln_final_f32(const u16* __restrict__ xin,
                                                    const u16* __restrict__ delta,
                                                    const float* __restrict__ g,
                                                    const float* __restrict__ b,
                                                    float* __restrict__ out) {
    int row = blockIdx.x * 256 + threadIdx.x;
    if (row >= L_TOK) return;
    size_t base = (size_t)row * 256;
    float sum = 0.f, sq = 0.f;
    for (int d = 0; d < 256; d++) {
        float v = bf2f(xin[base + d]) + bf2f(delta[base + d]);
        sum += v; sq += v * v;
    }
    float m = sum * (1.f / 256.f);
    float var = sq * (1.f / 256.f) - m * m;
    float r = rsqrtf(var + 1e-5f);
    for (int d = 0; d < 256; d++) {
        float v = bf2f(xin[base + d]) + bf2f(delta[base + d]);
        out[base + d] = (v - m) * r * g[d] + b[d];
    }
}

extern "C" void kernel_launch(void* const* d_in, const int* in_sizes, int n_in,
                              void* d_out, int out_size, void* d_ws, size_t ws_size,
                              hipStream_t stream) {
    const size_t MiB = 1048576;
    float* outp = (float*)d_out;
    int fillg = (out_size + 255) / 256;

    // ---- environment sentinels ----
    const int exp_sizes[18] = {4194304, 4194304, 131072, 512, 16384, 64, 102400, 400,
                               131072, 512, 524288, 2048, 524288, 512, 512, 512, 512, 512};
    bool env_ok = (n_in == 18) && (ws_size >= 25 * MiB) && (out_size == 4194304);
    if (env_ok) for (int i = 0; i < 18; i++) env_ok = env_ok && (in_sizes[i] == exp_sizes[i]);
    if (!env_ok) {
        hipLaunchKernelGGL(fill_kernel, dim3(fillg), dim3(256), 0, stream, outp, out_size, 3000.f);
        return;
    }

    const float* srcp  = (const float*)d_in[0];
    const float* posp  = (const float*)d_in[1];
    const float* Wv    = (const float*)d_in[2];
    const float* bv    = (const float*)d_in[3];
    const float* Wbox  = (const float*)d_in[4];
    const float* bbox  = (const float*)d_in[5];
    const float* Wattn = (const float*)d_in[6];
    const float* battn = (const float*)d_in[7];
    const float* Wo    = (const float*)d_in[8];
    const float* bo    = (const float*)d_in[9];
    const float* W1    = (const float*)d_in[10];
    const float* b1    = (const float*)d_in[11];
    const float* W2    = (const float*)d_in[12];
    const float* b2    = (const float*)d_in[13];
    const float* ln1g  = (const float*)d_in[14];
    const float* ln1b  = (const float*)d_in[15];
    const float* ln2g  = (const float*)d_in[16];
    const float* ln2b  = (const float*)d_in[17];

    char* ws = (char*)d_ws;
    // x: [0,8M)  q/val/hidden: [8,16M)  aw+ofb -> tmp -> ffnout: [16,24M)
    u16* x      = (u16*)(ws + 0);
    u16* q      = (u16*)(ws + 8 * MiB);
    u16* val    = (u16*)(ws + 8 * MiB);
    u16* hidden = (u16*)(ws + 8 * MiB);
    u16* aw     = (u16*)(ws + 16 * MiB);
    u16* ofb    = (u16*)(ws + 16 * MiB + 6553600);
    u16* tmp    = (u16*)(ws + 16 * MiB);
    u16* ffnout = (u16*)(ws + 16 * MiB);
    u16* attn   = (u16*)d_out;   // scratch in d_out (bf16 region, 8 MiB of 16 MiB);
                                 // fully consumed before the final f32 write overwrites it

    const int ND = L_TOK * DMODEL;

    auto G = [&](const u16* A, const float* W, const float* bias, u16* C,
                 int M, int N, int K, int relu) {
        int total = M * N;
        hipLaunchKernelGGL(gemm_naive, dim3((total + 255) / 256), dim3(256), 0, stream,
                           A, W, bias, C, M, N, K, relu);
    };

    // x = src^T  (natural (C,HW) -> (L,D))
    hipLaunchKernelGGL(xpose_kernel, dim3((ND + 255) / 256), dim3(256), 0, stream, srcp, x);

    for (int i = 0; i < 2; i++) {
        hipLaunchKernelGGL(addq_kernel, dim3((ND + 255) / 256), dim3(256), 0, stream,
                           x, posp, q);

        G(q, Wattn + (size_t)i * 51200, battn + (size_t)i * 200, aw, L_TOK, 200, 256, 0);
        G(q, Wbox + (size_t)i * 8192, bbox + (size_t)i * 32, ofb, L_TOK, 32, 256, 0);
        hipLaunchKernelGGL(softmax_kernel, dim3((L_TOK * NHEAD + 255) / 256), dim3(256), 0,
                           stream, aw, L_TOK * NHEAD);

        G(x, Wv + (size_t)i * 65536, bv + (size_t)i * 256, val, L_TOK, 256, 256, 0);

        hipLaunchKernelGGL(sample_kernel, dim3(ND / 256), dim3(256), 0, stream,
                           val, aw, ofb, attn);

        G(attn, Wo + (size_t)i * 65536, bo + (size_t)i * 256, tmp, L_TOK, 256, 256, 0);

        hipLaunchKernelGGL(ln_naive, dim3(64), dim3(256), 0, stream,
                           x, tmp, ln1g + (size_t)i * 256, ln1b + (size_t)i * 256, x);

        for (int mc = 0; mc < 4; mc++) {
            const u16* xa = x + (size_t)mc * 4096 * 256;
            u16* ya = ffnout + (size_t)mc * 4096 * 256;
            G(xa, W1 + (size_t)i * 262144, b1 + (size_t)i * 1024, hidden, 4096, 1024, 256, 1);
            G(hidden, W2 + (size_t)i * 262144, b2 + (size_t)i * 256, ya, 4096, 256, 1024, 0);
        }

        if (i == 0) {
            hipLaunchKernelGGL(ln_naive, dim3(64), dim3(256), 0, stream,
                               x, ffnout, ln2g, ln2b, x);
        } else {
            // FINAL: float32 output
            hipLaunchKernelGGL(ln_final_f32, dim3(64), dim3(256), 0, stream,
                               x, ffnout, ln2g + 256, ln2b + 256, outp);
        }
    }
}